// Round 1
// baseline (303.991 us; speedup 1.0000x reference)
//
#include <hip/hip_runtime.h>

#define HIN 192
#define WOUT 384
#define NIN 32
#define NOUT 16

__global__ __launch_bounds__(256) void steered_convT(
    const float* __restrict__ x,       // (8,32,192,192)
    const float* __restrict__ alpha,   // (2,8,1,384,384)
    const float* __restrict__ weights, // (16,32,9)
    const float* __restrict__ bias,    // (16,)
    float* __restrict__ out)           // (8,16,384,384)
{
    // ---- per-block: build the 15 basis kernels (5x5) into LDS ----
    // slots: 0..2 = b0 rings r0=0,1,2
    //        3+(k-1)*4+{0,1} = cos(k*th)*ring(1),ring(2)
    //        3+(k-1)*4+{2,3} = sin(k*th)*ring(1),ring(2)
    __shared__ float sb[15 * 25];
    for (int q = threadIdx.x; q < 375; q += 256) {
        int s = q / 25, p = q % 25;
        int ky = p / 5, kx = p % 5;
        float ys = (float)(ky - 2), xs = (float)(kx - 2);
        float r = sqrtf(xs * xs + ys * ys);
        float th = atan2f(ys, xs);
        float val;
        if (s < 3) {
            float d = r - (float)s;
            val = expf(-d * d * (1.0f / 0.72f));
        } else {
            int k = (s - 3) / 4 + 1;
            int rem = (s - 3) & 3;
            float r0 = (rem & 1) ? 2.0f : 1.0f;
            float d = r - r0;
            float ring = expf(-d * d * (1.0f / 0.72f));
            float ang = (float)k * th;
            val = ring * ((rem < 2) ? cosf(ang) : sinf(ang));
        }
        sb[q] = val;
    }
    __syncthreads();

    int idx = blockIdx.x * 256 + threadIdx.x;
    int ox = idx % WOUT;
    int tt = idx / WOUT;
    int oy = tt % WOUT;
    int n  = tt / WOUT;

    // ---- per-pixel angular coefficients from alpha ----
    const int plane = WOUT * WOUT;
    int aoff = (n * WOUT + oy) * WOUT + ox;
    float a0 = alpha[aoff];
    float a1 = alpha[8 * plane + aoff];
    float rho = sqrtf(a0 * a0 + a1 * a1);
    float inv = 1.0f / (rho + 1e-8f);
    float c1 = a0 * inv, s1 = a1 * inv;
    float c2 = c1 * c1 - s1 * s1, s2 = s1 * c1 + c1 * s1;
    float c3 = c2 * c1 - s2 * s1, s3 = s2 * c1 + c2 * s1;

    // ---- tap geometry: iy = (oy>>1)+1-ty, ky = (oy&1)+2*ty (invalid -> mask 0) ----
    int py = oy & 1, px = ox & 1;
    int iy0 = (oy >> 1) + 1;
    int ix0 = (ox >> 1) + 1;

    float eb[9][9];   // effective per-pixel basis, angular coefs + masks folded in
    int   off[9];     // clamped tap offsets within one input plane
    #pragma unroll
    for (int t = 0; t < 9; ++t) {
        int ty = t / 3, tx = t % 3;
        int ky = py + 2 * ty, kx = px + 2 * tx;
        int iy = iy0 - ty, ix = ix0 - tx;
        bool v = (ky < 5) && (kx < 5) && (iy >= 0) && (iy < HIN) && (ix >= 0) && (ix < HIN);
        float m = v ? 1.0f : 0.0f;
        int ciy = min(max(iy, 0), HIN - 1), cix = min(max(ix, 0), HIN - 1);
        off[t] = ciy * HIN + cix;
        int bi_ = min(ky, 4) * 5 + min(kx, 4);
        float B0  = sb[0 * 25 + bi_], B1  = sb[1 * 25 + bi_], B2  = sb[2 * 25 + bi_];
        float R10 = sb[3 * 25 + bi_], R11 = sb[4 * 25 + bi_];
        float I10 = sb[5 * 25 + bi_], I11 = sb[6 * 25 + bi_];
        float R20 = sb[7 * 25 + bi_], R21 = sb[8 * 25 + bi_];
        float I20 = sb[9 * 25 + bi_], I21 = sb[10 * 25 + bi_];
        float R30 = sb[11 * 25 + bi_], R31 = sb[12 * 25 + bi_];
        float I30 = sb[13 * 25 + bi_], I31 = sb[14 * 25 + bi_];
        eb[0][t] = B0 * m;
        eb[1][t] = B1 * m;
        eb[2][t] = B2 * m;
        eb[3][t] = (R10 * c1 + I10 * s1) * m;
        eb[4][t] = (R11 * c1 + I11 * s1) * m;
        eb[5][t] = (R20 * c2 + I20 * s2) * m;
        eb[6][t] = (R21 * c2 + I21 * s2) * m;
        eb[7][t] = (R30 * c3 + I30 * s3) * m;
        eb[8][t] = (R31 * c3 + I31 * s3) * m;
    }

    float acc[NOUT];
    #pragma unroll
    for (int o = 0; o < NOUT; ++o) acc[o] = 0.0f;

    const float* xn = x + (size_t)n * NIN * HIN * HIN;
    for (int i = 0; i < NIN; ++i) {
        const float* xp = xn + (size_t)i * HIN * HIN;
        float tap[9];
        #pragma unroll
        for (int t = 0; t < 9; ++t) tap[t] = xp[off[t]];
        float G[9];
        #pragma unroll
        for (int b = 0; b < 9; ++b) {
            float s = 0.0f;
            #pragma unroll
            for (int t = 0; t < 9; ++t) s += eb[b][t] * tap[t];
            G[b] = s;
        }
        // channel mix: W[o][i][b] — indices wave-uniform -> scalar loads
        const float* wp = weights + i * 9;
        #pragma unroll
        for (int o = 0; o < NOUT; ++o) {
            float s = acc[o];
            #pragma unroll
            for (int b = 0; b < 9; ++b) s += wp[o * NIN * 9 + b] * G[b];
            acc[o] = s;
        }
    }

    #pragma unroll
    for (int o = 0; o < NOUT; ++o) {
        out[((size_t)(n * NOUT + o) * WOUT + oy) * WOUT + ox] = rho * acc[o] + bias[o];
    }
}

extern "C" void kernel_launch(void* const* d_in, const int* in_sizes, int n_in,
                              void* d_out, int out_size, void* d_ws, size_t ws_size,
                              hipStream_t stream) {
    const float* x       = (const float*)d_in[0];
    const float* alpha   = (const float*)d_in[1];
    const float* weights = (const float*)d_in[2];
    const float* bias    = (const float*)d_in[3];
    float* out = (float*)d_out;

    const int pixels = 8 * WOUT * WOUT;          // 1,179,648
    dim3 grid(pixels / 256);                     // 4608 blocks, exact cover
    steered_convT<<<grid, 256, 0, stream>>>(x, alpha, weights, bias, out);
}